// Round 3
// baseline (103.308 us; speedup 1.0000x reference)
//
#include <hip/hip_runtime.h>
#include <hip/hip_bf16.h>

// Problem: B=16384, D=4096, fp32.
// out = mean_i( sum_j w[j] * |in[i,j] - t[i,j]| )
// Memory-bound: 536.9 MB of HBM reads -> ~77-85 us floor.
//
// R2: fix compile error — __builtin_nontemporal_load needs a native vector
// type, not HIP's float4 class. Use ext_vector_type(4).
// R1 changes vs R0 (103 us):
//  - hoist w4 load out of the loop (index tid&1023 is stride-invariant)
//  - compile-time stride/trip-count (32 iters) + unroll 8 -> 16 loads in flight
//  - nontemporal loads on the streamed a/b arrays

typedef float v4f __attribute__((ext_vector_type(4)));

#define B_ROWS 16384
#define D_COLS 4096
#define NV4    ((B_ROWS * (long long)D_COLS) / 4)   // 16777216 float4 elements
#define D4     (D_COLS / 4)                          // 1024 float4 per row
#define NBLK   2048
#define NTHR   256
#define STRIDE (NBLK * NTHR)                         // 524288, multiple of D4
#define ITERS  (NV4 / STRIDE)                        // 32

__global__ __launch_bounds__(NTHR) void l1w_partial(
    const v4f* __restrict__ a,
    const v4f* __restrict__ b,
    const v4f* __restrict__ w4,
    float* __restrict__ partial)
{
    int tid = blockIdx.x * NTHR + threadIdx.x;

    // stride (524288) is a multiple of D4 (1024), so t & (D4-1) is invariant
    const v4f wv = w4[tid & (D4 - 1)];

    float acc = 0.0f;
    #pragma unroll 8
    for (int it = 0; it < ITERS; ++it) {
        long long t = (long long)it * STRIDE + tid;
        v4f av = __builtin_nontemporal_load(&a[t]);
        v4f bv = __builtin_nontemporal_load(&b[t]);
        acc = fmaf(wv.x, fabsf(av.x - bv.x), acc);
        acc = fmaf(wv.y, fabsf(av.y - bv.y), acc);
        acc = fmaf(wv.z, fabsf(av.z - bv.z), acc);
        acc = fmaf(wv.w, fabsf(av.w - bv.w), acc);
    }

    // wave-64 reduce
    #pragma unroll
    for (int off = 32; off > 0; off >>= 1)
        acc += __shfl_down(acc, off, 64);

    __shared__ float s[NTHR / 64];
    int lane = threadIdx.x & 63;
    int wid  = threadIdx.x >> 6;
    if (lane == 0) s[wid] = acc;
    __syncthreads();
    if (threadIdx.x == 0) {
        float r = s[0];
        #pragma unroll
        for (int i = 1; i < NTHR / 64; ++i) r += s[i];
        partial[blockIdx.x] = r;
    }
}

__global__ __launch_bounds__(NTHR) void l1w_final(
    const float* __restrict__ partial,
    float* __restrict__ out,
    int n)
{
    float acc = 0.0f;
    for (int i = threadIdx.x; i < n; i += NTHR)
        acc += partial[i];

    #pragma unroll
    for (int off = 32; off > 0; off >>= 1)
        acc += __shfl_down(acc, off, 64);

    __shared__ float s[NTHR / 64];
    int lane = threadIdx.x & 63;
    int wid  = threadIdx.x >> 6;
    if (lane == 0) s[wid] = acc;
    __syncthreads();
    if (threadIdx.x == 0) {
        float r = s[0];
        #pragma unroll
        for (int i = 1; i < NTHR / 64; ++i) r += s[i];
        out[0] = r * (1.0f / (float)B_ROWS);
    }
}

extern "C" void kernel_launch(void* const* d_in, const int* in_sizes, int n_in,
                              void* d_out, int out_size, void* d_ws, size_t ws_size,
                              hipStream_t stream) {
    const v4f* a   = (const v4f*)d_in[0];   // inputs  [B, D]
    const v4f* b   = (const v4f*)d_in[1];   // targets [B, D]
    const v4f* w4  = (const v4f*)d_in[2];   // w [D]
    float* partial = (float*)d_ws;          // NBLK floats (8 KB)
    float* out     = (float*)d_out;

    l1w_partial<<<NBLK, NTHR, 0, stream>>>(a, b, w4, partial);
    l1w_final<<<1, NTHR, 0, stream>>>(partial, out, NBLK);
}

// Round 4
// 88.830 us; speedup vs baseline: 1.1630x; 1.1630x over previous
//
#include <hip/hip_runtime.h>
#include <hip/hip_bf16.h>

// Problem: B=16384, D=4096, fp32.
// out = mean_i( sum_j w[j] * |in[i,j] - t[i,j]| )
// Memory-bound: 536.9 MB of HBM reads.
//
// R3 (this round): block-contiguous chunking — each block streams one
// 128 KiB contiguous region of a and b (DRAM row locality) instead of
// 8 MiB grid-stride hops. w fully hoisted to 4 registers (index pattern
// is periodic-4 within a chunk).
// R0: 102.95 us  R2 (grid-stride + unroll8 + nt): 103.3 us (neutral)

typedef float v4f __attribute__((ext_vector_type(4)));

#define B_ROWS 16384
#define D_COLS 4096
#define NV4    ((B_ROWS * (long long)D_COLS) / 4)   // 16777216 float4 elements
#define D4     (D_COLS / 4)                          // 1024 float4 per row
#define NBLK   2048
#define NTHR   256
#define CHUNK  (NV4 / NBLK)                          // 8192 float4 = 128 KiB per block
#define ITERS  (CHUNK / NTHR)                        // 32

__global__ __launch_bounds__(NTHR) void l1w_partial(
    const v4f* __restrict__ a,
    const v4f* __restrict__ b,
    const v4f* __restrict__ w4,
    float* __restrict__ partial)
{
    const int t0 = threadIdx.x;
    const long long base = (long long)blockIdx.x * CHUNK;

    // chunk base is a multiple of D4 (8192 % 1024 == 0), so within a chunk
    // the w index is ((it*NTHR + t0) & 1023) = (it&3)*256 + t0 — 4 values.
    const v4f w0 = w4[t0];
    const v4f w1 = w4[t0 + 256];
    const v4f w2 = w4[t0 + 512];
    const v4f w3 = w4[t0 + 768];

    float acc = 0.0f;
    #pragma unroll 8
    for (int it = 0; it < ITERS; ++it) {
        long long t = base + (long long)it * NTHR + t0;
        v4f av = __builtin_nontemporal_load(&a[t]);
        v4f bv = __builtin_nontemporal_load(&b[t]);
        // (it & 3) is compile-time under unroll 8 -> select folds to a register
        v4f wv = ((it & 3) == 0) ? w0 : ((it & 3) == 1) ? w1 : ((it & 3) == 2) ? w2 : w3;
        acc = fmaf(wv.x, fabsf(av.x - bv.x), acc);
        acc = fmaf(wv.y, fabsf(av.y - bv.y), acc);
        acc = fmaf(wv.z, fabsf(av.z - bv.z), acc);
        acc = fmaf(wv.w, fabsf(av.w - bv.w), acc);
    }

    // wave-64 reduce
    #pragma unroll
    for (int off = 32; off > 0; off >>= 1)
        acc += __shfl_down(acc, off, 64);

    __shared__ float s[NTHR / 64];
    int lane = threadIdx.x & 63;
    int wid  = threadIdx.x >> 6;
    if (lane == 0) s[wid] = acc;
    __syncthreads();
    if (threadIdx.x == 0) {
        float r = s[0];
        #pragma unroll
        for (int i = 1; i < NTHR / 64; ++i) r += s[i];
        partial[blockIdx.x] = r;
    }
}

__global__ __launch_bounds__(NTHR) void l1w_final(
    const float* __restrict__ partial,
    float* __restrict__ out,
    int n)
{
    float acc = 0.0f;
    for (int i = threadIdx.x; i < n; i += NTHR)
        acc += partial[i];

    #pragma unroll
    for (int off = 32; off > 0; off >>= 1)
        acc += __shfl_down(acc, off, 64);

    __shared__ float s[NTHR / 64];
    int lane = threadIdx.x & 63;
    int wid  = threadIdx.x >> 6;
    if (lane == 0) s[wid] = acc;
    __syncthreads();
    if (threadIdx.x == 0) {
        float r = s[0];
        #pragma unroll
        for (int i = 1; i < NTHR / 64; ++i) r += s[i];
        out[0] = r * (1.0f / (float)B_ROWS);
    }
}

extern "C" void kernel_launch(void* const* d_in, const int* in_sizes, int n_in,
                              void* d_out, int out_size, void* d_ws, size_t ws_size,
                              hipStream_t stream) {
    const v4f* a   = (const v4f*)d_in[0];   // inputs  [B, D]
    const v4f* b   = (const v4f*)d_in[1];   // targets [B, D]
    const v4f* w4  = (const v4f*)d_in[2];   // w [D]
    float* partial = (float*)d_ws;          // NBLK floats (8 KB)
    float* out     = (float*)d_out;

    l1w_partial<<<NBLK, NTHR, 0, stream>>>(a, b, w4, partial);
    l1w_final<<<1, NTHR, 0, stream>>>(partial, out, NBLK);
}